// Round 1
// baseline (184352.405 us; speedup 1.0000x reference)
//
#include <hip/hip_runtime.h>
#include <hip/hip_cooperative_groups.h>

namespace cg = cooperative_groups;

constexpr int TT = 2048;   // timesteps
constexpr int NB = 128;    // batch
constexpr int NI = 64;     // input size
constexpr int NH = 256;    // hidden

__device__ __forceinline__ float sigm(float v) { return 1.0f / (1.0f + __expf(-v)); }

// Accumulate z[0..3] += W[g] dot h_col(b) over K=256, h stored transposed [k][b].
__device__ __forceinline__ void dot_trans256(
    const float* __restrict__ hsrc, int b,
    const float* __restrict__ w0, const float* __restrict__ w1,
    const float* __restrict__ w2, const float* __restrict__ w3,
    float& z0, float& z1, float& z2, float& z3)
{
    const float4* W0 = (const float4*)w0;
    const float4* W1 = (const float4*)w1;
    const float4* W2 = (const float4*)w2;
    const float4* W3 = (const float4*)w3;
    #pragma unroll 8
    for (int k4 = 0; k4 < NH / 4; ++k4) {
        const float* hp = hsrc + k4 * 4 * NB + b;
        float hv0 = hp[0];
        float hv1 = hp[NB];
        float hv2 = hp[2 * NB];
        float hv3 = hp[3 * NB];
        float4 w;
        w = W0[k4]; z0 += w.x * hv0 + w.y * hv1 + w.z * hv2 + w.w * hv3;
        w = W1[k4]; z1 += w.x * hv0 + w.y * hv1 + w.z * hv2 + w.w * hv3;
        w = W2[k4]; z2 += w.x * hv0 + w.y * hv1 + w.z * hv2 + w.w * hv3;
        w = W3[k4]; z3 += w.x * hv0 + w.y * hv1 + w.z * hv2 + w.w * hv3;
    }
}

// Grid: 256 WGs x 256 threads.
//   WG  0..127  -> layer 0, pipeline phase s computes h0(s)       (+ head for t=s-2)
//   WG 128..255 -> layer 1, pipeline phase s computes h1(s-1)
// Thread (tid) in WG wgl owns pair: b = tid&127, j = 2*wgl + (tid>>7).
// h buffers double-buffered, stored transposed [buf][k][b]; h(t) lives in buf t&1.
// Cell state c stays in a register for the whole sequence.
__global__ void __launch_bounds__(256, 1) lstm2(
    const float* __restrict__ x,
    const float* __restrict__ h0in, const float* __restrict__ c0in,
    const float* __restrict__ Wih0, const float* __restrict__ Whh0,
    const float* __restrict__ bih0, const float* __restrict__ bhh0,
    const float* __restrict__ Wih1, const float* __restrict__ Whh1,
    const float* __restrict__ bih1, const float* __restrict__ bhh1,
    const float* __restrict__ Wlin, const float* __restrict__ blin,
    float* __restrict__ out,
    float* __restrict__ h0T, float* __restrict__ h1T)
{
    cg::grid_group grid = cg::this_grid();
    const int wg  = blockIdx.x;
    const int tid = threadIdx.x;
    const bool is1 = (wg >= 128);
    const int wgl = is1 ? (wg - 128) : wg;
    const int b   = tid & 127;
    const int jj  = tid >> 7;
    const int j   = __builtin_amdgcn_readfirstlane(wgl * 2 + jj);  // wave-uniform

    const int r0 = 0 * NH + j, r1 = 1 * NH + j, r2 = 2 * NH + j, r3 = 3 * NH + j;

    // Wave-uniform weight-row pointers -> scalar loads in the K loop.
    const float *wx0, *wx1, *wx2, *wx3, *wh0, *wh1, *wh2, *wh3;
    float bias0, bias1, bias2, bias3;
    if (!is1) {
        wx0 = Wih0 + (size_t)r0 * NI; wx1 = Wih0 + (size_t)r1 * NI;
        wx2 = Wih0 + (size_t)r2 * NI; wx3 = Wih0 + (size_t)r3 * NI;
        wh0 = Whh0 + (size_t)r0 * NH; wh1 = Whh0 + (size_t)r1 * NH;
        wh2 = Whh0 + (size_t)r2 * NH; wh3 = Whh0 + (size_t)r3 * NH;
        bias0 = bih0[r0] + bhh0[r0]; bias1 = bih0[r1] + bhh0[r1];
        bias2 = bih0[r2] + bhh0[r2]; bias3 = bih0[r3] + bhh0[r3];
    } else {
        wx0 = Wih1 + (size_t)r0 * NH; wx1 = Wih1 + (size_t)r1 * NH;
        wx2 = Wih1 + (size_t)r2 * NH; wx3 = Wih1 + (size_t)r3 * NH;
        wh0 = Whh1 + (size_t)r0 * NH; wh1 = Whh1 + (size_t)r1 * NH;
        wh2 = Whh1 + (size_t)r2 * NH; wh3 = Whh1 + (size_t)r3 * NH;
        bias0 = bih1[r0] + bhh1[r0]; bias1 = bih1[r1] + bhh1[r1];
        bias2 = bih1[r2] + bhh1[r2]; bias3 = bih1[r3] + bhh1[r3];
    }

    // persistent cell state
    float c = c0in[(is1 ? 1 : 0) * NB * NH + b * NH + j];

    // h(-1) -> buffer 1 (phase 0 / t=0 reads buf (t-1)&1 == 1)
    float* myh = is1 ? h1T : h0T;
    myh[1 * NH * NB + j * NB + b] = h0in[(is1 ? 1 : 0) * NB * NH + b * NH + j];

    __threadfence();
    grid.sync();

    for (int s = 0; s <= TT + 1; ++s) {
        if (!is1) {
            if (s < TT) {
                // ---- layer 0, step s ----
                float z0 = bias0, z1 = bias1, z2 = bias2, z3 = bias3;
                const float4* xr = (const float4*)(x + (size_t)s * NB * NI + (size_t)b * NI);
                const float4* X0 = (const float4*)wx0;
                const float4* X1 = (const float4*)wx1;
                const float4* X2 = (const float4*)wx2;
                const float4* X3 = (const float4*)wx3;
                #pragma unroll
                for (int k4 = 0; k4 < NI / 4; ++k4) {
                    float4 xv = xr[k4];
                    float4 w;
                    w = X0[k4]; z0 += w.x * xv.x + w.y * xv.y + w.z * xv.z + w.w * xv.w;
                    w = X1[k4]; z1 += w.x * xv.x + w.y * xv.y + w.z * xv.z + w.w * xv.w;
                    w = X2[k4]; z2 += w.x * xv.x + w.y * xv.y + w.z * xv.z + w.w * xv.w;
                    w = X3[k4]; z3 += w.x * xv.x + w.y * xv.y + w.z * xv.z + w.w * xv.w;
                }
                dot_trans256(h0T + ((size_t)((s - 1) & 1)) * NH * NB, b,
                             wh0, wh1, wh2, wh3, z0, z1, z2, z3);
                float ig = sigm(z0), fg = sigm(z1), gg = tanhf(z2), og = sigm(z3);
                c = fg * c + ig * gg;
                float hn = og * tanhf(c);
                h0T[(size_t)(s & 1) * NH * NB + j * NB + b] = hn;
            }
            // ---- head for t = s-2 (h1(s-2) became visible after last sync) ----
            if (s >= 2 && tid < 64) {
                int u = s - 2;
                const float* hc = h1T + (size_t)(u & 1) * NH * NB + wgl;
                float p = hc[(size_t)tid * NB]         * Wlin[tid]
                        + hc[(size_t)(tid + 64) * NB]  * Wlin[tid + 64]
                        + hc[(size_t)(tid + 128) * NB] * Wlin[tid + 128]
                        + hc[(size_t)(tid + 192) * NB] * Wlin[tid + 192];
                #pragma unroll
                for (int off = 32; off; off >>= 1) p += __shfl_down(p, off);
                if (tid == 0) out[(size_t)u * NB + wgl] = p + blin[0];
            }
        } else {
            if (s >= 1 && s <= TT) {
                // ---- layer 1, step t = s-1 ----
                int t = s - 1;
                float z0 = bias0, z1 = bias1, z2 = bias2, z3 = bias3;
                // input part: h0(t), transposed buffer
                dot_trans256(h0T + (size_t)(t & 1) * NH * NB, b,
                             wx0, wx1, wx2, wx3, z0, z1, z2, z3);
                // recurrent part: h1(t-1)
                dot_trans256(h1T + (size_t)((t - 1) & 1) * NH * NB, b,
                             wh0, wh1, wh2, wh3, z0, z1, z2, z3);
                float ig = sigm(z0), fg = sigm(z1), gg = tanhf(z2), og = sigm(z3);
                c = fg * c + ig * gg;
                float hn = og * tanhf(c);
                h1T[(size_t)(t & 1) * NH * NB + j * NB + b] = hn;
            }
        }
        __threadfence();
        grid.sync();
    }
}

extern "C" void kernel_launch(void* const* d_in, const int* in_sizes, int n_in,
                              void* d_out, int out_size, void* d_ws, size_t ws_size,
                              hipStream_t stream)
{
    const float* x    = (const float*)d_in[0];
    const float* h0in = (const float*)d_in[1];
    const float* c0in = (const float*)d_in[2];
    const float* Wih0 = (const float*)d_in[3];
    const float* Whh0 = (const float*)d_in[4];
    const float* bih0 = (const float*)d_in[5];
    const float* bhh0 = (const float*)d_in[6];
    const float* Wih1 = (const float*)d_in[7];
    const float* Whh1 = (const float*)d_in[8];
    const float* bih1 = (const float*)d_in[9];
    const float* bhh1 = (const float*)d_in[10];
    const float* Wlin = (const float*)d_in[11];
    const float* blin = (const float*)d_in[12];
    float* out = (float*)d_out;

    float* h0T = (float*)d_ws;                 // [2][NH][NB]
    float* h1T = h0T + 2 * NH * NB;            // [2][NH][NB]

    void* args[] = { &x, &h0in, &c0in, &Wih0, &Whh0, &bih0, &bhh0,
                     &Wih1, &Whh1, &bih1, &bhh1, &Wlin, &blin,
                     &out, &h0T, &h1T };
    hipLaunchCooperativeKernel((void*)lstm2, dim3(256), dim3(256), args, 0, stream);
}

// Round 2
// 82066.943 us; speedup vs baseline: 2.2464x; 2.2464x over previous
//
#include <hip/hip_runtime.h>

constexpr int TT  = 2048;   // timesteps
constexpr int NB  = 128;    // batch
constexpr int NI  = 64;     // input size
constexpr int NH  = 256;    // hidden
constexpr int NWG = 128;    // 64 layer-0 WGs + 64 layer-1 WGs
constexpr int NTHR = 512;   // 4 j-slots x 128 b
constexpr int NPHASE = TT + 2;  // 2050 compute phases (pipelined)

// Barrier state in device globals: zero-init at load, self-reset at final phase,
// so graph replays see a clean state without any memset.
__device__ unsigned g_cnt = 0;
__device__ unsigned g_gen = 0;

__device__ __forceinline__ float sigm(float v) { return 1.0f / (1.0f + __expf(-v)); }

// Monotonic grid barrier: k-th call (k = 1..KLAST) waits until all NWG arrive.
// Leader-only fence: leader shares L1 (per-CU) and L2 (per-XCD) with its WG,
// so its agent-scope acq_rel fence covers the whole WG's visibility needs.
__device__ __forceinline__ void gridbar(unsigned k, bool last) {
    __syncthreads();                       // drains vmcnt -> WG stores are in L2
    if (threadIdx.x == 0) {
        __threadfence();                   // agent release: L2 -> coherence point
        unsigned a = __hip_atomic_fetch_add(&g_cnt, 1u, __ATOMIC_ACQ_REL,
                                            __HIP_MEMORY_SCOPE_AGENT);
        if (a == k * NWG - 1u) {
            if (last) {
                __hip_atomic_store(&g_cnt, 0u, __ATOMIC_RELAXED, __HIP_MEMORY_SCOPE_AGENT);
                __hip_atomic_store(&g_gen, 0u, __ATOMIC_RELEASE, __HIP_MEMORY_SCOPE_AGENT);
            } else {
                __hip_atomic_store(&g_gen, k, __ATOMIC_RELEASE, __HIP_MEMORY_SCOPE_AGENT);
            }
        } else if (!last) {
            while (__hip_atomic_load(&g_gen, __ATOMIC_RELAXED,
                                     __HIP_MEMORY_SCOPE_AGENT) < k)
                __builtin_amdgcn_s_sleep(1);
        }
        __threadfence();                   // agent acquire: inv L1/L2 -> fresh h reads
    }
    __syncthreads();
}

// WGs 0..63: layer 0 (+ linear head, 2 batch cols each).
// WGs 64..127: layer 1.
// Thread (tid): b = tid&127, jl = tid>>7 (0..3), j = wgl*4 + jl.
// Waves are j-uniform -> all weight LDS reads are broadcasts (conflict-free).
// h buffers double-buffered in ws, layout [slot][k][b] (k-major, b contiguous
// -> fully coalesced lane reads). Cell state c lives in a register all 2048 steps.
__global__ void __launch_bounds__(NTHR, 2) lstm2(
    const float* __restrict__ x,
    const float* __restrict__ h0in, const float* __restrict__ c0in,
    const float* __restrict__ Wih0, const float* __restrict__ Whh0,
    const float* __restrict__ bih0, const float* __restrict__ bhh0,
    const float* __restrict__ Wih1, const float* __restrict__ Whh1,
    const float* __restrict__ bih1, const float* __restrict__ bhh1,
    const float* __restrict__ Wlin, const float* __restrict__ blin,
    float* __restrict__ out,
    float* __restrict__ h0T, float* __restrict__ h1T)
{
    // LDS: 16 weight rows per WG for each of ih/hh (layer-1: 16x256 each = 32 KB)
    __shared__ __align__(16) float wih_lds[16 * NH];   // layer-0 uses 16*NI of it
    __shared__ __align__(16) float whh_lds[16 * NH];
    __shared__ float wlin_lds[NH];
    __shared__ float red[8];

    const int wg   = blockIdx.x;
    const int tid  = threadIdx.x;
    const bool is1 = (wg >= 64);
    const int wgl  = is1 ? wg - 64 : wg;
    const int b    = tid & 127;
    const int jl   = tid >> 7;            // 0..3, wave-uniform
    const int j    = wgl * 4 + jl;        // global hidden index
    const int wg4  = wgl * 4;

    // ---- stage weights into LDS ----
    if (!is1) {
        for (int e = tid; e < 16 * NI; e += NTHR) {       // Wih0: 16 rows x 64
            int r = e >> 6, k = e & 63;
            int jr = r >> 2, g = r & 3;
            wih_lds[e] = Wih0[(size_t)(g * NH + wg4 + jr) * NI + k];
        }
        for (int e = tid; e < 16 * NH; e += NTHR) {       // Whh0: 16 rows x 256
            int r = e >> 8, k = e & 255;
            int jr = r >> 2, g = r & 3;
            whh_lds[e] = Whh0[(size_t)(g * NH + wg4 + jr) * NH + k];
        }
        for (int e = tid; e < NH; e += NTHR) wlin_lds[e] = Wlin[e];
    } else {
        for (int e = tid; e < 16 * NH; e += NTHR) {       // Wih1: 16 rows x 256
            int r = e >> 8, k = e & 255;
            int jr = r >> 2, g = r & 3;
            wih_lds[e] = Wih1[(size_t)(g * NH + wg4 + jr) * NH + k];
        }
        for (int e = tid; e < 16 * NH; e += NTHR) {       // Whh1: 16 rows x 256
            int r = e >> 8, k = e & 255;
            int jr = r >> 2, g = r & 3;
            whh_lds[e] = Whh1[(size_t)(g * NH + wg4 + jr) * NH + k];
        }
    }

    // per-thread biases and init state
    float bias0, bias1, bias2, bias3, c;
    {
        const float* bi = is1 ? bih1 : bih0;
        const float* bh = is1 ? bhh1 : bhh0;
        bias0 = bi[0 * NH + j] + bh[0 * NH + j];
        bias1 = bi[1 * NH + j] + bh[1 * NH + j];
        bias2 = bi[2 * NH + j] + bh[2 * NH + j];
        bias3 = bi[3 * NH + j] + bh[3 * NH + j];
        c = c0in[(is1 ? 1 : 0) * NB * NH + b * NH + j];
        // h(-1) -> slot 1
        float* myh = is1 ? h1T : h0T;
        myh[1 * NH * NB + j * NB + b] = h0in[(is1 ? 1 : 0) * NB * NH + b * NH + j];
    }
    const float blv = blin[0];

    gridbar(1, false);   // publish initial h + finish LDS staging

    const float4* W4i = (const float4*)wih_lds;
    const float4* W4h = (const float4*)whh_lds;
    const int rbH = jl * 4 * (NH / 4);    // float4 row base, pitch 64
    const int rbI = jl * 4 * (NI / 4);    // float4 row base, pitch 16

    for (int p = 0; p < NPHASE; ++p) {
        if (!is1) {
            if (p < TT) {
                // ---- layer 0, step p ----
                float z0 = bias0, z1 = bias1, z2 = bias2, z3 = bias3;
                const float4* xv4 = (const float4*)(x + (size_t)p * NB * NI + (size_t)b * NI);
                #pragma unroll
                for (int k4 = 0; k4 < NI / 4; ++k4) {
                    float4 xv = xv4[k4];
                    float4 w;
                    w = W4i[rbI + 0 * 16 + k4]; z0 += w.x*xv.x + w.y*xv.y + w.z*xv.z + w.w*xv.w;
                    w = W4i[rbI + 1 * 16 + k4]; z1 += w.x*xv.x + w.y*xv.y + w.z*xv.z + w.w*xv.w;
                    w = W4i[rbI + 2 * 16 + k4]; z2 += w.x*xv.x + w.y*xv.y + w.z*xv.z + w.w*xv.w;
                    w = W4i[rbI + 3 * 16 + k4]; z3 += w.x*xv.x + w.y*xv.y + w.z*xv.z + w.w*xv.w;
                }
                const float* hsrc = h0T + (size_t)((p + 1) & 1) * NH * NB;  // h0(p-1)
                #pragma unroll 8
                for (int k4 = 0; k4 < NH / 4; ++k4) {
                    const float* hp = hsrc + k4 * 4 * NB + b;
                    float a0 = hp[0], a1 = hp[NB], a2 = hp[2 * NB], a3 = hp[3 * NB];
                    float4 w;
                    w = W4h[rbH + 0 * 64 + k4]; z0 += w.x*a0 + w.y*a1 + w.z*a2 + w.w*a3;
                    w = W4h[rbH + 1 * 64 + k4]; z1 += w.x*a0 + w.y*a1 + w.z*a2 + w.w*a3;
                    w = W4h[rbH + 2 * 64 + k4]; z2 += w.x*a0 + w.y*a1 + w.z*a2 + w.w*a3;
                    w = W4h[rbH + 3 * 64 + k4]; z3 += w.x*a0 + w.y*a1 + w.z*a2 + w.w*a3;
                }
                float ig = sigm(z0), fg = sigm(z1), gg = tanhf(z2), og = sigm(z3);
                c = fg * c + ig * gg;
                float hn = og * tanhf(c);
                h0T[(size_t)(p & 1) * NH * NB + j * NB + b] = hn;
            }
            if (p >= 2) {
                // ---- head for t = p-2 : out[t][b] = Wlin . h1(t)[:,b] + blin ----
                int t = p - 2;
                const float* hc = h1T + (size_t)(t & 1) * NH * NB;
                int k = tid & 255;
                int bb = wgl * 2 + (tid >> 8);
                float partial = hc[(size_t)k * NB + bb] * wlin_lds[k];
                #pragma unroll
                for (int off = 32; off; off >>= 1) partial += __shfl_down(partial, off);
                if ((tid & 63) == 0) red[tid >> 6] = partial;
                __syncthreads();
                if (tid == 0)   out[(size_t)t * NB + wgl * 2]     = red[0] + red[1] + red[2] + red[3] + blv;
                if (tid == 256) out[(size_t)t * NB + wgl * 2 + 1] = red[4] + red[5] + red[6] + red[7] + blv;
            }
        } else {
            if (p >= 1 && p <= TT) {
                // ---- layer 1, step t = p-1 ----
                float z0 = bias0, z1 = bias1, z2 = bias2, z3 = bias3;
                const float* h0src = h0T + (size_t)((p + 1) & 1) * NH * NB;  // h0(t)
                #pragma unroll 8
                for (int k4 = 0; k4 < NH / 4; ++k4) {
                    const float* hp = h0src + k4 * 4 * NB + b;
                    float a0 = hp[0], a1 = hp[NB], a2 = hp[2 * NB], a3 = hp[3 * NB];
                    float4 w;
                    w = W4i[rbH + 0 * 64 + k4]; z0 += w.x*a0 + w.y*a1 + w.z*a2 + w.w*a3;
                    w = W4i[rbH + 1 * 64 + k4]; z1 += w.x*a0 + w.y*a1 + w.z*a2 + w.w*a3;
                    w = W4i[rbH + 2 * 64 + k4]; z2 += w.x*a0 + w.y*a1 + w.z*a2 + w.w*a3;
                    w = W4i[rbH + 3 * 64 + k4]; z3 += w.x*a0 + w.y*a1 + w.z*a2 + w.w*a3;
                }
                const float* h1src = h1T + (size_t)(p & 1) * NH * NB;        // h1(t-1)
                #pragma unroll 8
                for (int k4 = 0; k4 < NH / 4; ++k4) {
                    const float* hp = h1src + k4 * 4 * NB + b;
                    float a0 = hp[0], a1 = hp[NB], a2 = hp[2 * NB], a3 = hp[3 * NB];
                    float4 w;
                    w = W4h[rbH + 0 * 64 + k4]; z0 += w.x*a0 + w.y*a1 + w.z*a2 + w.w*a3;
                    w = W4h[rbH + 1 * 64 + k4]; z1 += w.x*a0 + w.y*a1 + w.z*a2 + w.w*a3;
                    w = W4h[rbH + 2 * 64 + k4]; z2 += w.x*a0 + w.y*a1 + w.z*a2 + w.w*a3;
                    w = W4h[rbH + 3 * 64 + k4]; z3 += w.x*a0 + w.y*a1 + w.z*a2 + w.w*a3;
                }
                float ig = sigm(z0), fg = sigm(z1), gg = tanhf(z2), og = sigm(z3);
                c = fg * c + ig * gg;
                float hn = og * tanhf(c);
                h1T[(size_t)((p + 1) & 1) * NH * NB + j * NB + b] = hn;
            }
        }
        gridbar((unsigned)(p + 2), p == NPHASE - 1);
    }
}

extern "C" void kernel_launch(void* const* d_in, const int* in_sizes, int n_in,
                              void* d_out, int out_size, void* d_ws, size_t ws_size,
                              hipStream_t stream)
{
    const float* x    = (const float*)d_in[0];
    const float* h0in = (const float*)d_in[1];
    const float* c0in = (const float*)d_in[2];
    const float* Wih0 = (const float*)d_in[3];
    const float* Whh0 = (const float*)d_in[4];
    const float* bih0 = (const float*)d_in[5];
    const float* bhh0 = (const float*)d_in[6];
    const float* Wih1 = (const float*)d_in[7];
    const float* Whh1 = (const float*)d_in[8];
    const float* bih1 = (const float*)d_in[9];
    const float* bhh1 = (const float*)d_in[10];
    const float* Wlin = (const float*)d_in[11];
    const float* blin = (const float*)d_in[12];
    float* out = (float*)d_out;

    float* h0T = (float*)d_ws;                 // [2][NH][NB]
    float* h1T = h0T + 2 * NH * NB;            // [2][NH][NB]

    void* args[] = { &x, &h0in, &c0in, &Wih0, &Whh0, &bih0, &bhh0,
                     &Wih1, &Whh1, &bih1, &bhh1, &Wlin, &blin,
                     &out, &h0T, &h1T };
    hipLaunchCooperativeKernel((void*)lstm2, dim3(NWG), dim3(NTHR), args, 0, stream);
}

// Round 3
// 52619.928 us; speedup vs baseline: 3.5035x; 1.5596x over previous
//
#include <hip/hip_runtime.h>

constexpr int TT = 2048;   // timesteps
constexpr int NB = 128;    // batch
constexpr int NI = 64;     // input size
constexpr int NH = 256;    // hidden
constexpr int NGRP = 128;  // WGs per layer
constexpr int NWG  = 2 * NGRP;
constexpr int NTHR = 512;
constexpr int S0   = 4;    // h0 ring slots (layer 0 may run <=3 steps ahead)
constexpr int FSTR = 32;   // flag stride in uints (128 B -> own cacheline)

// Flag arrays + end-barrier state. Zero at load; self-reset at kernel end,
// so graph replays always start from a clean state.
__device__ unsigned g_flag0[NGRP * FSTR];
__device__ unsigned g_flag1[NGRP * FSTR];
__device__ unsigned g_cnt = 0;
__device__ unsigned g_gen = 0;

__device__ __forceinline__ float sigm(float v) { return 1.0f / (1.0f + __expf(-v)); }

// Counter barrier (used ONLY twice at kernel end for the flag reset).
__device__ __forceinline__ void gridbar(unsigned k, bool last) {
    __syncthreads();
    if (threadIdx.x == 0) {
        __threadfence();
        unsigned a = __hip_atomic_fetch_add(&g_cnt, 1u, __ATOMIC_ACQ_REL,
                                            __HIP_MEMORY_SCOPE_AGENT);
        if (a == k * NWG - 1u) {
            if (last) {
                __hip_atomic_store(&g_cnt, 0u, __ATOMIC_RELAXED, __HIP_MEMORY_SCOPE_AGENT);
                __hip_atomic_store(&g_gen, 0u, __ATOMIC_RELEASE, __HIP_MEMORY_SCOPE_AGENT);
            } else {
                __hip_atomic_store(&g_gen, k, __ATOMIC_RELEASE, __HIP_MEMORY_SCOPE_AGENT);
            }
        } else if (!last) {
            while (__hip_atomic_load(&g_gen, __ATOMIC_RELAXED,
                                     __HIP_MEMORY_SCOPE_AGENT) < k)
                __builtin_amdgcn_s_sleep(1);
        }
        __threadfence();
    }
    __syncthreads();
}

// Distributed barrier wait: waves 0-1 poll the 128 own-group flags (>= vown),
// waves 2-3 poll the 128 cross-group flags (>= vcross, 0 = skip). One flag per
// lane, read-only polling -> no RMW serialization. Acquire fence by the polling
// waves invalidates this CU's L1 (+ stale L2) before the barrier releases.
__device__ __forceinline__ void phase_wait(unsigned* own, unsigned vown,
                                           unsigned* cross, unsigned vcross) {
    const int w = threadIdx.x >> 6;
    if (w < 4) {
        unsigned* f = (w < 2) ? own : cross;
        unsigned v  = (w < 2) ? vown : vcross;
        if (v) {
            unsigned* p = f + (((w & 1) << 6) + (threadIdx.x & 63)) * FSTR;
            for (;;) {
                unsigned xv = __hip_atomic_load(p, __ATOMIC_RELAXED,
                                                __HIP_MEMORY_SCOPE_AGENT);
                if (__all((int)(xv >= v))) break;
                __builtin_amdgcn_s_sleep(2);
            }
        }
        __builtin_amdgcn_fence(__ATOMIC_ACQUIRE, "agent");
    }
    __syncthreads();
}

// One FMA block: 8 weight rows (2 j x 4 gates) x one k, two b columns.
#define STEPQ(Q, HA, HB)                                   \
    acc[0]  += w00.Q * (HA); acc[1]  += w00.Q * (HB);      \
    acc[2]  += w01.Q * (HA); acc[3]  += w01.Q * (HB);      \
    acc[4]  += w02.Q * (HA); acc[5]  += w02.Q * (HB);      \
    acc[6]  += w03.Q * (HA); acc[7]  += w03.Q * (HB);      \
    acc[8]  += w10.Q * (HA); acc[9]  += w10.Q * (HB);      \
    acc[10] += w11.Q * (HA); acc[11] += w11.Q * (HB);      \
    acc[12] += w12.Q * (HA); acc[13] += w12.Q * (HB);      \
    acc[14] += w13.Q * (HA); acc[15] += w13.Q * (HB);

#define LOADW(W, K, kk)                                                        \
    float4 w00 = *(const float4*)((W) + (size_t)(0 * NH + j0    ) * (K) + (kk)); \
    float4 w01 = *(const float4*)((W) + (size_t)(1 * NH + j0    ) * (K) + (kk)); \
    float4 w02 = *(const float4*)((W) + (size_t)(2 * NH + j0    ) * (K) + (kk)); \
    float4 w03 = *(const float4*)((W) + (size_t)(3 * NH + j0    ) * (K) + (kk)); \
    float4 w10 = *(const float4*)((W) + (size_t)(0 * NH + j0 + 1) * (K) + (kk)); \
    float4 w11 = *(const float4*)((W) + (size_t)(1 * NH + j0 + 1) * (K) + (kk)); \
    float4 w12 = *(const float4*)((W) + (size_t)(2 * NH + j0 + 1) * (K) + (kk)); \
    float4 w13 = *(const float4*)((W) + (size_t)(3 * NH + j0 + 1) * (K) + (kk));

// Partial dot over a 64-long k slice of h stored [k][b] (b contiguous).
__device__ __forceinline__ void partialA(const float* __restrict__ W, int K,
                                         int j0, int k0,
                                         const float* __restrict__ hsrc,
                                         int lane, float* acc) {
    const float* hp = hsrc + (size_t)k0 * NB + (lane << 1);
    #pragma unroll 4
    for (int i4 = 0; i4 < 16; ++i4) {
        const int kk = k0 + (i4 << 2);
        LOADW(W, K, kk)
        float2 h0v = *(const float2*)(hp + (size_t)(kk - k0 + 0) * NB);
        float2 h1v = *(const float2*)(hp + (size_t)(kk - k0 + 1) * NB);
        float2 h2v = *(const float2*)(hp + (size_t)(kk - k0 + 2) * NB);
        float2 h3v = *(const float2*)(hp + (size_t)(kk - k0 + 3) * NB);
        STEPQ(x, h0v.x, h0v.y)
        STEPQ(y, h1v.x, h1v.y)
        STEPQ(z, h2v.x, h2v.y)
        STEPQ(w, h3v.x, h3v.y)
    }
}

// Partial dot over a 16-long k slice of x stored [b][k] (k contiguous).
__device__ __forceinline__ void partialB(const float* __restrict__ W,
                                         int j0, int k0,
                                         const float* __restrict__ xp,
                                         int lane, float* acc) {
    #pragma unroll
    for (int i4 = 0; i4 < 4; ++i4) {
        const int kk = k0 + (i4 << 2);
        LOADW(W, NI, kk)
        float4 xa = *(const float4*)(xp + (size_t)(lane << 1) * NI + kk);
        float4 xb = *(const float4*)(xp + (size_t)((lane << 1) + 1) * NI + kk);
        STEPQ(x, xa.x, xb.x)
        STEPQ(y, xa.y, xb.y)
        STEPQ(z, xa.z, xb.z)
        STEPQ(w, xa.w, xb.w)
    }
}

// Grid: 256 WGs x 512 threads. WGs 0..127 -> layer 0, 128..255 -> layer 1.
// WG g owns hidden rows j0=2g, 2g+1 (8 gate-rows). Wave = k-slot (64 k each),
// lane = b-pair. Partials meet in LDS; combine threads own (b, j) and keep c
// in a register for all 2048 steps. h buffers in ws: h0 ring of 4, h1 ring of 2,
// layout [slot][k][b].
__global__ void __launch_bounds__(NTHR, 2) lstm2(
    const float* __restrict__ x,
    const float* __restrict__ h0in, const float* __restrict__ c0in,
    const float* __restrict__ Wih0, const float* __restrict__ Whh0,
    const float* __restrict__ bih0, const float* __restrict__ bhh0,
    const float* __restrict__ Wih1, const float* __restrict__ Whh1,
    const float* __restrict__ bih1, const float* __restrict__ bhh1,
    const float* __restrict__ Wlin, const float* __restrict__ blin,
    float* __restrict__ out,
    float* __restrict__ h0T, float* __restrict__ h1T)
{
    __shared__ __align__(16) float4 zp4[8 * 2 * NB];  // [slot][jl][b] gates in comps, 32 KB
    __shared__ float red[4];

    const int tid  = threadIdx.x;
    const int wg   = blockIdx.x;
    const bool is1 = (wg >= NGRP);
    const int g    = is1 ? wg - NGRP : wg;
    const int lane = tid & 63;
    const int wv   = tid >> 6;          // 0..7 = k-slot
    const int j0   = g * 2;

    // combine-role mapping
    const int cb  = tid & 127;
    const int csl = tid >> 7;           // 0..3
    const int cjl = csl & 1;
    const int cj  = j0 + cjl;

    unsigned* ownf   = is1 ? g_flag1 : g_flag0;
    unsigned* crossf = is1 ? g_flag0 : g_flag1;

    // biases, init state
    const float* bi = is1 ? bih1 : bih0;
    const float* bh = is1 ? bhh1 : bhh0;
    const float bs0 = bi[0 * NH + cj] + bh[0 * NH + cj];
    const float bs1 = bi[1 * NH + cj] + bh[1 * NH + cj];
    const float bs2 = bi[2 * NH + cj] + bh[2 * NH + cj];
    const float bs3 = bi[3 * NH + cj] + bh[3 * NH + cj];
    float c = c0in[(is1 ? 1 : 0) * NB * NH + cb * NH + cj];
    const float blv = blin[0];

    // publish h(-1)
    {
        float* hT = is1 ? h1T : h0T;
        const int islot = is1 ? 1 : (S0 - 1);
        if (csl < 2)
            hT[(size_t)islot * NH * NB + (size_t)cj * NB + cb] =
                h0in[(is1 ? 1 : 0) * NB * NH + cb * NH + cj];
    }
    __syncthreads();
    if (tid == 0)
        __hip_atomic_store(ownf + g * FSTR, 1u, __ATOMIC_RELEASE,
                           __HIP_MEMORY_SCOPE_AGENT);

    if (!is1) {
        // ================= layer 0 =================
        for (int s = 0; s < TT; ++s) {
            unsigned vc = ((unsigned)(s + 2) > (unsigned)S0)
                              ? (unsigned)(s + 2 - S0) : 0u;
            phase_wait(ownf, (unsigned)(s + 1), crossf, vc);

            float acc[16] = {0,0,0,0,0,0,0,0,0,0,0,0,0,0,0,0};
            if (wv < 4)
                partialA(Whh0, NH, j0, wv << 6,
                         h0T + (size_t)((s + 3) & 3) * NH * NB, lane, acc);
            else
                partialB(Wih0, j0, (wv - 4) << 4,
                         x + (size_t)s * NB * NI, lane, acc);

            const int base0 = ((wv << 1) + 0) * NB + (lane << 1);
            const int base1 = ((wv << 1) + 1) * NB + (lane << 1);
            zp4[base0]     = make_float4(acc[0],  acc[2],  acc[4],  acc[6]);
            zp4[base0 + 1] = make_float4(acc[1],  acc[3],  acc[5],  acc[7]);
            zp4[base1]     = make_float4(acc[8],  acc[10], acc[12], acc[14]);
            zp4[base1 + 1] = make_float4(acc[9],  acc[11], acc[13], acc[15]);
            __syncthreads();

            float z0 = bs0, z1 = bs1, z2 = bs2, z3 = bs3;
            #pragma unroll
            for (int sl = 0; sl < 8; ++sl) {
                float4 v = zp4[((sl << 1) + cjl) * NB + cb];
                z0 += v.x; z1 += v.y; z2 += v.z; z3 += v.w;
            }
            float ig = sigm(z0), fg = sigm(z1), gg = tanhf(z2), og = sigm(z3);
            c = fg * c + ig * gg;
            float hn = og * tanhf(c);
            if (csl < 2)
                h0T[(size_t)(s & 3) * NH * NB + (size_t)cj * NB + cb] = hn;
            __syncthreads();
            if (tid == 0)
                __hip_atomic_store(ownf + g * FSTR, (unsigned)(s + 2),
                                   __ATOMIC_RELEASE, __HIP_MEMORY_SCOPE_AGENT);
        }
    } else {
        // ================= layer 1 (+ head) =================
        for (int t = 0; t < TT; ++t) {
            phase_wait(ownf, (unsigned)(t + 1), crossf, (unsigned)(t + 2));

            if (t >= 1) {   // head for u = t-1 (h1(t-1) just became visible)
                const int u = t - 1;
                const float* hc = h1T + (size_t)(u & 1) * NH * NB;
                if (tid < NH) {
                    float p = Wlin[tid] * hc[(size_t)tid * NB + g];
                    #pragma unroll
                    for (int off = 32; off; off >>= 1) p += __shfl_down(p, off);
                    if ((tid & 63) == 0) red[tid >> 6] = p;
                }
                __syncthreads();
                if (tid == 0)
                    out[(size_t)u * NB + g] = red[0] + red[1] + red[2] + red[3] + blv;
            }

            float acc[16] = {0,0,0,0,0,0,0,0,0,0,0,0,0,0,0,0};
            if (wv < 4)
                partialA(Wih1, NH, j0, wv << 6,
                         h0T + (size_t)(t & 3) * NH * NB, lane, acc);
            else
                partialA(Whh1, NH, j0, (wv - 4) << 6,
                         h1T + (size_t)((t + 1) & 1) * NH * NB, lane, acc);

            const int base0 = ((wv << 1) + 0) * NB + (lane << 1);
            const int base1 = ((wv << 1) + 1) * NB + (lane << 1);
            zp4[base0]     = make_float4(acc[0],  acc[2],  acc[4],  acc[6]);
            zp4[base0 + 1] = make_float4(acc[1],  acc[3],  acc[5],  acc[7]);
            zp4[base1]     = make_float4(acc[8],  acc[10], acc[12], acc[14]);
            zp4[base1 + 1] = make_float4(acc[9],  acc[11], acc[13], acc[15]);
            __syncthreads();

            float z0 = bs0, z1 = bs1, z2 = bs2, z3 = bs3;
            #pragma unroll
            for (int sl = 0; sl < 8; ++sl) {
                float4 v = zp4[((sl << 1) + cjl) * NB + cb];
                z0 += v.x; z1 += v.y; z2 += v.z; z3 += v.w;
            }
            float ig = sigm(z0), fg = sigm(z1), gg = tanhf(z2), og = sigm(z3);
            c = fg * c + ig * gg;
            float hn = og * tanhf(c);
            if (csl < 2)
                h1T[(size_t)(t & 1) * NH * NB + (size_t)cj * NB + cb] = hn;
            __syncthreads();
            if (tid == 0)
                __hip_atomic_store(ownf + g * FSTR, (unsigned)(t + 2),
                                   __ATOMIC_RELEASE, __HIP_MEMORY_SCOPE_AGENT);
        }

        // final head: u = TT-1
        phase_wait(ownf, (unsigned)(TT + 1), ownf, 0u);
        {
            const int u = TT - 1;
            const float* hc = h1T + (size_t)(u & 1) * NH * NB;
            if (tid < NH) {
                float p = Wlin[tid] * hc[(size_t)tid * NB + g];
                #pragma unroll
                for (int off = 32; off; off >>= 1) p += __shfl_down(p, off);
                if ((tid & 63) == 0) red[tid >> 6] = p;
            }
            __syncthreads();
            if (tid == 0)
                out[(size_t)u * NB + g] = red[0] + red[1] + red[2] + red[3] + blv;
        }
    }

    // ---- end protocol: reset flags behind a real barrier (graph-replay safe) ----
    gridbar(1, false);
    if (tid == 0)
        __hip_atomic_store(ownf + g * FSTR, 0u, __ATOMIC_RELAXED,
                           __HIP_MEMORY_SCOPE_AGENT);
    gridbar(2, true);
}

extern "C" void kernel_launch(void* const* d_in, const int* in_sizes, int n_in,
                              void* d_out, int out_size, void* d_ws, size_t ws_size,
                              hipStream_t stream)
{
    const float* x    = (const float*)d_in[0];
    const float* h0in = (const float*)d_in[1];
    const float* c0in = (const float*)d_in[2];
    const float* Wih0 = (const float*)d_in[3];
    const float* Whh0 = (const float*)d_in[4];
    const float* bih0 = (const float*)d_in[5];
    const float* bhh0 = (const float*)d_in[6];
    const float* Wih1 = (const float*)d_in[7];
    const float* Whh1 = (const float*)d_in[8];
    const float* bih1 = (const float*)d_in[9];
    const float* bhh1 = (const float*)d_in[10];
    const float* Wlin = (const float*)d_in[11];
    const float* blin = (const float*)d_in[12];
    float* out = (float*)d_out;

    float* h0T = (float*)d_ws;                  // [4][NH][NB]
    float* h1T = h0T + (size_t)S0 * NH * NB;    // [2][NH][NB]

    void* args[] = { &x, &h0in, &c0in, &Wih0, &Whh0, &bih0, &bhh0,
                     &Wih1, &Whh1, &bih1, &bhh1, &Wlin, &blin,
                     &out, &h0T, &h1T };
    hipLaunchCooperativeKernel((void*)lstm2, dim3(NWG), dim3(NTHR), args, 0, stream);
}

// Round 4
// 24979.286 us; speedup vs baseline: 7.3802x; 2.1065x over previous
//
#include <hip/hip_runtime.h>

constexpr int TT = 2048;   // timesteps
constexpr int NB = 128;    // batch
constexpr int NI = 64;     // input size
constexpr int NH = 256;    // hidden
constexpr int NGRP = 128;  // WGs per layer
constexpr int NWG  = 2 * NGRP;
constexpr int NTHR = 512;
constexpr int S0   = 4;    // h0 ring slots (layer 0 may run <=3 steps ahead)
constexpr int FSTR = 32;   // flag stride in uints (128 B -> own cacheline)

// Flag arrays + end-barrier state. Zero at load; self-reset at kernel end,
// so graph replays always start from a clean state.
__device__ unsigned g_flag0[NGRP * FSTR];
__device__ unsigned g_flag1[NGRP * FSTR];
__device__ unsigned g_cnt = 0;
__device__ unsigned g_gen = 0;

__device__ __forceinline__ float sigm(float v) { return 1.0f / (1.0f + __expf(-v)); }

// ---- LLC-coherent (agent-scope, relaxed) accessors for cross-WG h data.
// These bypass the incoherent L1/L2 via sc bits; NO fences needed -> the
// per-step L2 invalidations (round-3's killer) disappear and weights stay
// L2-resident.
__device__ __forceinline__ float2 ldh2(const float* p) {
    unsigned long long u = __hip_atomic_load((const unsigned long long*)p,
                                             __ATOMIC_RELAXED,
                                             __HIP_MEMORY_SCOPE_AGENT);
    union { unsigned long long u; float2 f; } cv; cv.u = u; return cv.f;
}
__device__ __forceinline__ float ldh1(const float* p) {
    return __hip_atomic_load(p, __ATOMIC_RELAXED, __HIP_MEMORY_SCOPE_AGENT);
}
__device__ __forceinline__ void sth(float* p, float v) {
    __hip_atomic_store(p, v, __ATOMIC_RELAXED, __HIP_MEMORY_SCOPE_AGENT);
}

// Counter barrier (used ONLY twice at kernel end for the flag reset).
__device__ __forceinline__ void gridbar(unsigned k, bool last) {
    __syncthreads();
    if (threadIdx.x == 0) {
        __threadfence();
        unsigned a = __hip_atomic_fetch_add(&g_cnt, 1u, __ATOMIC_ACQ_REL,
                                            __HIP_MEMORY_SCOPE_AGENT);
        if (a == k * NWG - 1u) {
            if (last) {
                __hip_atomic_store(&g_cnt, 0u, __ATOMIC_RELAXED, __HIP_MEMORY_SCOPE_AGENT);
                __hip_atomic_store(&g_gen, 0u, __ATOMIC_RELEASE, __HIP_MEMORY_SCOPE_AGENT);
            } else {
                __hip_atomic_store(&g_gen, k, __ATOMIC_RELEASE, __HIP_MEMORY_SCOPE_AGENT);
            }
        } else if (!last) {
            while (__hip_atomic_load(&g_gen, __ATOMIC_RELAXED,
                                     __HIP_MEMORY_SCOPE_AGENT) < k)
                __builtin_amdgcn_s_sleep(1);
        }
        __threadfence();
    }
    __syncthreads();
}

// Distributed wait: waves 0-1 poll the 128 own-group flags (>= vown), waves
// 2-3 poll the 128 cross-group flags (>= vcross, 0 = skip). One flag/lane,
// read-only polling, NO cache-invalidating fence (h data is LLC-coherent).
__device__ __forceinline__ void phase_wait(unsigned* own, unsigned vown,
                                           unsigned* cross, unsigned vcross) {
    const int w = threadIdx.x >> 6;
    if (w < 4) {
        unsigned* f = (w < 2) ? own : cross;
        unsigned v  = (w < 2) ? vown : vcross;
        if (v) {
            unsigned* p = f + (((w & 1) << 6) + (threadIdx.x & 63)) * FSTR;
            for (;;) {
                unsigned xv = __hip_atomic_load(p, __ATOMIC_RELAXED,
                                                __HIP_MEMORY_SCOPE_AGENT);
                if (__all((int)(xv >= v))) break;
                __builtin_amdgcn_s_sleep(2);
            }
        }
    }
    __syncthreads();
}

// One FMA block: 8 weight rows (2 j x 4 gates) x one k, two b columns.
#define STEPQ(Q, HA, HB)                                   \
    acc[0]  += w00.Q * (HA); acc[1]  += w00.Q * (HB);      \
    acc[2]  += w01.Q * (HA); acc[3]  += w01.Q * (HB);      \
    acc[4]  += w02.Q * (HA); acc[5]  += w02.Q * (HB);      \
    acc[6]  += w03.Q * (HA); acc[7]  += w03.Q * (HB);      \
    acc[8]  += w10.Q * (HA); acc[9]  += w10.Q * (HB);      \
    acc[10] += w11.Q * (HA); acc[11] += w11.Q * (HB);      \
    acc[12] += w12.Q * (HA); acc[13] += w12.Q * (HB);      \
    acc[14] += w13.Q * (HA); acc[15] += w13.Q * (HB);

// kk is wave-uniform (readfirstlane'd base) -> addresses are uniform ->
// compiler can emit s_load_dwordx4 (scalar cache), freeing the VMEM pipe.
#define LOADW(W, K, kk)                                                        \
    float4 w00 = *(const float4*)((W) + (size_t)(0 * NH + j0    ) * (K) + (kk)); \
    float4 w01 = *(const float4*)((W) + (size_t)(1 * NH + j0    ) * (K) + (kk)); \
    float4 w02 = *(const float4*)((W) + (size_t)(2 * NH + j0    ) * (K) + (kk)); \
    float4 w03 = *(const float4*)((W) + (size_t)(3 * NH + j0    ) * (K) + (kk)); \
    float4 w10 = *(const float4*)((W) + (size_t)(0 * NH + j0 + 1) * (K) + (kk)); \
    float4 w11 = *(const float4*)((W) + (size_t)(1 * NH + j0 + 1) * (K) + (kk)); \
    float4 w12 = *(const float4*)((W) + (size_t)(2 * NH + j0 + 1) * (K) + (kk)); \
    float4 w13 = *(const float4*)((W) + (size_t)(3 * NH + j0 + 1) * (K) + (kk));

// Partial dot over a 64-long k slice of h stored [k][b] (b contiguous).
__device__ __forceinline__ void partialA(const float* __restrict__ W, int K,
                                         int j0, int k0,
                                         const float* __restrict__ hsrc,
                                         int lane, float* acc) {
    const int k0u = __builtin_amdgcn_readfirstlane(k0);
    const float* hp = hsrc + (size_t)k0u * NB + (lane << 1);
    #pragma unroll 4
    for (int i4 = 0; i4 < 16; ++i4) {
        const int kk = k0u + (i4 << 2);
        LOADW(W, K, kk)
        float2 h0v = ldh2(hp + (size_t)((i4 << 2) + 0) * NB);
        float2 h1v = ldh2(hp + (size_t)((i4 << 2) + 1) * NB);
        float2 h2v = ldh2(hp + (size_t)((i4 << 2) + 2) * NB);
        float2 h3v = ldh2(hp + (size_t)((i4 << 2) + 3) * NB);
        STEPQ(x, h0v.x, h0v.y)
        STEPQ(y, h1v.x, h1v.y)
        STEPQ(z, h2v.x, h2v.y)
        STEPQ(w, h3v.x, h3v.y)
    }
}

// Partial dot over a 16-long k slice of x stored [b][k] (k contiguous).
// x is an immutable input -> normal cached loads.
__device__ __forceinline__ void partialB(const float* __restrict__ W,
                                         int j0, int k0,
                                         const float* __restrict__ xp,
                                         int lane, float* acc) {
    const int k0u = __builtin_amdgcn_readfirstlane(k0);
    #pragma unroll
    for (int i4 = 0; i4 < 4; ++i4) {
        const int kk = k0u + (i4 << 2);
        LOADW(W, NI, kk)
        float4 xa = *(const float4*)(xp + (size_t)(lane << 1) * NI + kk);
        float4 xb = *(const float4*)(xp + (size_t)((lane << 1) + 1) * NI + kk);
        STEPQ(x, xa.x, xb.x)
        STEPQ(y, xa.y, xb.y)
        STEPQ(z, xa.z, xb.z)
        STEPQ(w, xa.w, xb.w)
    }
}

// Grid: 256 WGs x 512 threads. WGs 0..127 -> layer 0, 128..255 -> layer 1.
// WG g owns hidden rows j0=2g, 2g+1 (8 gate-rows). Wave = k-slot (64 k each),
// lane = b-pair. Partials meet in LDS; combine threads own (b, j) and keep c
// in a register for all 2048 steps. h buffers in ws: h0 ring of 4, h1 ring of 2,
// layout [slot][k][b]; all h accesses LLC-coherent (no fences in hot loop).
__global__ void __launch_bounds__(NTHR, 2) lstm2(
    const float* __restrict__ x,
    const float* __restrict__ h0in, const float* __restrict__ c0in,
    const float* __restrict__ Wih0, const float* __restrict__ Whh0,
    const float* __restrict__ bih0, const float* __restrict__ bhh0,
    const float* __restrict__ Wih1, const float* __restrict__ Whh1,
    const float* __restrict__ bih1, const float* __restrict__ bhh1,
    const float* __restrict__ Wlin, const float* __restrict__ blin,
    float* __restrict__ out,
    float* __restrict__ h0T, float* __restrict__ h1T)
{
    __shared__ __align__(16) float4 zp4[8 * 2 * NB];  // [slot][jl][b] gates in comps, 32 KB
    __shared__ float red[4];

    const int tid  = threadIdx.x;
    const int wg   = blockIdx.x;
    const bool is1 = (wg >= NGRP);
    const int g    = is1 ? wg - NGRP : wg;
    const int lane = tid & 63;
    const int wv   = tid >> 6;          // 0..7 = k-slot
    const int j0   = g * 2;

    // combine-role mapping
    const int cb  = tid & 127;
    const int csl = tid >> 7;           // 0..3
    const int cjl = csl & 1;
    const int cj  = j0 + cjl;

    unsigned* ownf   = is1 ? g_flag1 : g_flag0;
    unsigned* crossf = is1 ? g_flag0 : g_flag1;

    // biases, init state
    const float* bi = is1 ? bih1 : bih0;
    const float* bh = is1 ? bhh1 : bhh0;
    const float bs0 = bi[0 * NH + cj] + bh[0 * NH + cj];
    const float bs1 = bi[1 * NH + cj] + bh[1 * NH + cj];
    const float bs2 = bi[2 * NH + cj] + bh[2 * NH + cj];
    const float bs3 = bi[3 * NH + cj] + bh[3 * NH + cj];
    float c = c0in[(is1 ? 1 : 0) * NB * NH + cb * NH + cj];
    const float blv = blin[0];

    // publish h(-1)
    {
        float* hT = is1 ? h1T : h0T;
        const int islot = is1 ? 1 : (S0 - 1);
        if (csl < 2)
            sth(&hT[(size_t)islot * NH * NB + (size_t)cj * NB + cb],
                h0in[(is1 ? 1 : 0) * NB * NH + cb * NH + cj]);
    }
    __syncthreads();
    if (tid == 0)
        __hip_atomic_store(ownf + g * FSTR, 1u, __ATOMIC_RELEASE,
                           __HIP_MEMORY_SCOPE_AGENT);

    if (!is1) {
        // ================= layer 0 =================
        for (int s = 0; s < TT; ++s) {
            unsigned vc = ((unsigned)(s + 2) > (unsigned)S0)
                              ? (unsigned)(s + 2 - S0) : 0u;
            phase_wait(ownf, (unsigned)(s + 1), crossf, vc);

            float acc[16] = {0,0,0,0,0,0,0,0,0,0,0,0,0,0,0,0};
            if (wv < 4)
                partialA(Whh0, NH, j0, wv << 6,
                         h0T + (size_t)((s + 3) & 3) * NH * NB, lane, acc);
            else
                partialB(Wih0, j0, (wv - 4) << 4,
                         x + (size_t)s * NB * NI, lane, acc);

            const int base0 = ((wv << 1) + 0) * NB + (lane << 1);
            const int base1 = ((wv << 1) + 1) * NB + (lane << 1);
            zp4[base0]     = make_float4(acc[0],  acc[2],  acc[4],  acc[6]);
            zp4[base0 + 1] = make_float4(acc[1],  acc[3],  acc[5],  acc[7]);
            zp4[base1]     = make_float4(acc[8],  acc[10], acc[12], acc[14]);
            zp4[base1 + 1] = make_float4(acc[9],  acc[11], acc[13], acc[15]);
            __syncthreads();

            float z0 = bs0, z1 = bs1, z2 = bs2, z3 = bs3;
            #pragma unroll
            for (int sl = 0; sl < 8; ++sl) {
                float4 v = zp4[((sl << 1) + cjl) * NB + cb];
                z0 += v.x; z1 += v.y; z2 += v.z; z3 += v.w;
            }
            float ig = sigm(z0), fg = sigm(z1), gg = tanhf(z2), og = sigm(z3);
            c = fg * c + ig * gg;
            float hn = og * tanhf(c);
            if (csl < 2)
                sth(&h0T[(size_t)(s & 3) * NH * NB + (size_t)cj * NB + cb], hn);
            __syncthreads();
            if (tid == 0)
                __hip_atomic_store(ownf + g * FSTR, (unsigned)(s + 2),
                                   __ATOMIC_RELEASE, __HIP_MEMORY_SCOPE_AGENT);
        }
    } else {
        // ================= layer 1 (+ head) =================
        for (int t = 0; t < TT; ++t) {
            phase_wait(ownf, (unsigned)(t + 1), crossf, (unsigned)(t + 2));

            if (t >= 1) {   // head for u = t-1 (h1(t-1) just became visible)
                const int u = t - 1;
                const float* hc = h1T + (size_t)(u & 1) * NH * NB;
                if (tid < NH) {
                    float p = Wlin[tid] * ldh1(hc + (size_t)tid * NB + g);
                    #pragma unroll
                    for (int off = 32; off; off >>= 1) p += __shfl_down(p, off);
                    if ((tid & 63) == 0) red[tid >> 6] = p;
                }
                __syncthreads();
                if (tid == 0)
                    out[(size_t)u * NB + g] = red[0] + red[1] + red[2] + red[3] + blv;
            }

            float acc[16] = {0,0,0,0,0,0,0,0,0,0,0,0,0,0,0,0};
            if (wv < 4)
                partialA(Wih1, NH, j0, wv << 6,
                         h0T + (size_t)(t & 3) * NH * NB, lane, acc);
            else
                partialA(Whh1, NH, j0, (wv - 4) << 6,
                         h1T + (size_t)((t + 1) & 1) * NH * NB, lane, acc);

            const int base0 = ((wv << 1) + 0) * NB + (lane << 1);
            const int base1 = ((wv << 1) + 1) * NB + (lane << 1);
            zp4[base0]     = make_float4(acc[0],  acc[2],  acc[4],  acc[6]);
            zp4[base0 + 1] = make_float4(acc[1],  acc[3],  acc[5],  acc[7]);
            zp4[base1]     = make_float4(acc[8],  acc[10], acc[12], acc[14]);
            zp4[base1 + 1] = make_float4(acc[9],  acc[11], acc[13], acc[15]);
            __syncthreads();

            float z0 = bs0, z1 = bs1, z2 = bs2, z3 = bs3;
            #pragma unroll
            for (int sl = 0; sl < 8; ++sl) {
                float4 v = zp4[((sl << 1) + cjl) * NB + cb];
                z0 += v.x; z1 += v.y; z2 += v.z; z3 += v.w;
            }
            float ig = sigm(z0), fg = sigm(z1), gg = tanhf(z2), og = sigm(z3);
            c = fg * c + ig * gg;
            float hn = og * tanhf(c);
            if (csl < 2)
                sth(&h1T[(size_t)(t & 1) * NH * NB + (size_t)cj * NB + cb], hn);
            __syncthreads();
            if (tid == 0)
                __hip_atomic_store(ownf + g * FSTR, (unsigned)(t + 2),
                                   __ATOMIC_RELEASE, __HIP_MEMORY_SCOPE_AGENT);
        }

        // final head: u = TT-1
        phase_wait(ownf, (unsigned)(TT + 1), ownf, 0u);
        {
            const int u = TT - 1;
            const float* hc = h1T + (size_t)(u & 1) * NH * NB;
            if (tid < NH) {
                float p = Wlin[tid] * ldh1(hc + (size_t)tid * NB + g);
                #pragma unroll
                for (int off = 32; off; off >>= 1) p += __shfl_down(p, off);
                if ((tid & 63) == 0) red[tid >> 6] = p;
            }
            __syncthreads();
            if (tid == 0)
                out[(size_t)u * NB + g] = red[0] + red[1] + red[2] + red[3] + blv;
        }
    }

    // ---- end protocol: reset flags behind a real barrier (graph-replay safe) ----
    gridbar(1, false);
    if (tid == 0)
        __hip_atomic_store(ownf + g * FSTR, 0u, __ATOMIC_RELAXED,
                           __HIP_MEMORY_SCOPE_AGENT);
    gridbar(2, true);
}

extern "C" void kernel_launch(void* const* d_in, const int* in_sizes, int n_in,
                              void* d_out, int out_size, void* d_ws, size_t ws_size,
                              hipStream_t stream)
{
    const float* x    = (const float*)d_in[0];
    const float* h0in = (const float*)d_in[1];
    const float* c0in = (const float*)d_in[2];
    const float* Wih0 = (const float*)d_in[3];
    const float* Whh0 = (const float*)d_in[4];
    const float* bih0 = (const float*)d_in[5];
    const float* bhh0 = (const float*)d_in[6];
    const float* Wih1 = (const float*)d_in[7];
    const float* Whh1 = (const float*)d_in[8];
    const float* bih1 = (const float*)d_in[9];
    const float* bhh1 = (const float*)d_in[10];
    const float* Wlin = (const float*)d_in[11];
    const float* blin = (const float*)d_in[12];
    float* out = (float*)d_out;

    float* h0T = (float*)d_ws;                  // [4][NH][NB]
    float* h1T = h0T + (size_t)S0 * NH * NB;    // [2][NH][NB]

    void* args[] = { &x, &h0in, &c0in, &Wih0, &Whh0, &bih0, &bhh0,
                     &Wih1, &Whh1, &bih1, &bhh1, &Wlin, &blin,
                     &out, &h0T, &h1T };
    hipLaunchCooperativeKernel((void*)lstm2, dim3(NWG), dim3(NTHR), args, 0, stream);
}